// Round 1
// baseline (386.773 us; speedup 1.0000x reference)
//
#include <hip/hip_runtime.h>
#include <hip/hip_bf16.h>
#include <math.h>

#define NB 16384          // batch
#define LCODES 32         // codes per bag
#define DD 128            // embedding dim
#define MED 1000          // output classes

typedef __bf16 bf16x8 __attribute__((ext_vector_type(8)));
typedef float  f32x4  __attribute__((ext_vector_type(4)));
typedef unsigned short u16;

__device__ __forceinline__ u16 f2bf(float f) {
    union { float f; unsigned u; } v; v.f = f;
    unsigned r = v.u + 0x7fffu + ((v.u >> 16) & 1u);   // RNE
    return (u16)(r >> 16);
}

// ---------------------------------------------------------------------------
// Convert weights fp32 -> bf16 (W3 padded to 1024 rows with zeros)
// total elements: 32768 (W1) + 65536 (W2) + 262144 (W3 padded) = 360448
// ---------------------------------------------------------------------------
__global__ __launch_bounds__(256) void convert_kernel(
    const float* __restrict__ W1, const float* __restrict__ W2,
    const float* __restrict__ W3,
    u16* __restrict__ W1b, u16* __restrict__ W2b, u16* __restrict__ W3b)
{
    int i = blockIdx.x * 256 + threadIdx.x;
    if (i < 32768) { W1b[i] = f2bf(W1[i]); return; }
    i -= 32768;
    if (i < 65536) { W2b[i] = f2bf(W2[i]); return; }
    i -= 65536;
    if (i < 262144) {
        W3b[i] = (i < MED * 256) ? f2bf(W3[i]) : (u16)0;
    }
}

// ---------------------------------------------------------------------------
// Gather + bag-sum. Block handles 2 batch rows. 256 threads:
//   t = sub*128 + bag*32 + c4 ; bag: 0=diag 1=proc 2=prev_diag 3=prev_proc
//   thread owns float4 column c4 (cols 4c4..4c4+3) of its bag, sums 32 rows.
// X[b,0:128]=diag_sum, X[b,128:256]=proc_sum ; Xp likewise for prev.
// ---------------------------------------------------------------------------
__global__ __launch_bounds__(256) void gather_kernel(
    const int* __restrict__ diag, const int* __restrict__ proc,
    const int* __restrict__ pdiag, const int* __restrict__ pproc,
    const float* __restrict__ demb, const float* __restrict__ pemb,
    u16* __restrict__ X, u16* __restrict__ Xp)
{
    __shared__ int sidx[256];
    const int t = threadIdx.x;
    const int sub = t >> 7;
    const int rem = t & 127;
    const int bag = rem >> 5;
    const int lc  = rem & 31;      // doubles as l (load phase) and c4 (compute)
    const int b = blockIdx.x * 2 + sub;

    const int* cp = (bag == 0) ? diag : (bag == 1) ? proc : (bag == 2) ? pdiag : pproc;
    sidx[t] = cp[b * LCODES + lc];
    __syncthreads();

    const float* table = (bag & 1) ? pemb : demb;
    const int* myidx = &sidx[sub * 128 + bag * 32];

    float sx = 0.f, sy = 0.f, sz = 0.f, sw = 0.f;
    #pragma unroll
    for (int i = 0; i < 32; ++i) {
        const int row = myidx[i];
        const float4 v = *(const float4*)(table + (size_t)row * DD + lc * 4);
        sx += v.x; sy += v.y; sz += v.z; sw += v.w;
    }

    u16* dst = ((bag < 2) ? X : Xp) + (size_t)b * 256 + (bag & 1) * 128 + lc * 4;
    uint2 o;
    o.x = (unsigned)f2bf(sx) | ((unsigned)f2bf(sy) << 16);
    o.y = (unsigned)f2bf(sz) | ((unsigned)f2bf(sw) << 16);
    *(uint2*)dst = o;
}

// ---------------------------------------------------------------------------
// TN GEMM, K=256 fixed, bf16 MFMA 16x16x32.
// A: [M,256] bf16 row-major.  W: [N,256] bf16 row-major (torch W[out,in]).
// Block = 256 thr = 4 waves. Block tile M=64 (wave strip M=16) x N=64.
// Wave: 4 accumulators along N (4 x 16x16 tiles), K-loop 8 steps of 32.
// A frag: A[m=lane&15][k=quad*8+j] ; B frag: W[n=lane&15][k=quad*8+j]
// C/D:    col = lane&15 (N), row = quad*4 + reg (M)   [guide §3, m89-verified]
// EPI 0: +bias, bf16 store with cur/prev mapping into rep[B,256]
// EPI 1: +bias, relu, bf16 store [M,256]
// EPI 2: +bias, sigmoid, fp32 store [M,1000], cols >= 1000 masked
// ---------------------------------------------------------------------------
template<int EPI>
__global__ __launch_bounds__(256) void gemm_bt(
    const u16* __restrict__ A, const u16* __restrict__ W,
    const float* __restrict__ bias, void* __restrict__ outp, int brows)
{
    const int wave = threadIdx.x >> 6;
    const int lane = threadIdx.x & 63;
    const int quad = lane >> 4;
    const int l16  = lane & 15;
    const int mA    = blockIdx.x * 64 + wave * 16 + l16;  // A row for a-frag
    const int nBase = blockIdx.y * 64;

    const u16* aP = A + (size_t)mA * 256 + quad * 8;
    const u16* wP = W + (size_t)(nBase + l16) * 256 + quad * 8;

    f32x4 acc0 = {0.f,0.f,0.f,0.f}, acc1 = {0.f,0.f,0.f,0.f};
    f32x4 acc2 = {0.f,0.f,0.f,0.f}, acc3 = {0.f,0.f,0.f,0.f};

    #pragma unroll
    for (int ks = 0; ks < 8; ++ks) {
        const bf16x8 a  = *(const bf16x8*)(aP + ks * 32);
        const bf16x8 b0 = *(const bf16x8*)(wP + ks * 32);
        const bf16x8 b1 = *(const bf16x8*)(wP + 16 * 256 + ks * 32);
        const bf16x8 b2 = *(const bf16x8*)(wP + 32 * 256 + ks * 32);
        const bf16x8 b3 = *(const bf16x8*)(wP + 48 * 256 + ks * 32);
        acc0 = __builtin_amdgcn_mfma_f32_16x16x32_bf16(a, b0, acc0, 0, 0, 0);
        acc1 = __builtin_amdgcn_mfma_f32_16x16x32_bf16(a, b1, acc1, 0, 0, 0);
        acc2 = __builtin_amdgcn_mfma_f32_16x16x32_bf16(a, b2, acc2, 0, 0, 0);
        acc3 = __builtin_amdgcn_mfma_f32_16x16x32_bf16(a, b3, acc3, 0, 0, 0);
    }

    const int rowBase = blockIdx.x * 64 + wave * 16 + quad * 4;
    f32x4 accs[4] = {acc0, acc1, acc2, acc3};

    #pragma unroll
    for (int nt = 0; nt < 4; ++nt) {
        const int col = nBase + nt * 16 + l16;
        f32x4 acc = accs[nt];
        if (EPI == 2) {
            if (col < MED) {
                const float bv = bias[col];
                float* out = (float*)outp;
                #pragma unroll
                for (int r = 0; r < 4; ++r) {
                    const float v = acc[r] + bv;
                    out[(size_t)(rowBase + r) * MED + col] = 1.0f / (1.0f + __expf(-v));
                }
            }
        } else if (EPI == 1) {
            const float bv = bias[col];
            u16* out = (u16*)outp;
            #pragma unroll
            for (int r = 0; r < 4; ++r) {
                float v = acc[r] + bv;
                v = v > 0.f ? v : 0.f;
                out[(size_t)(rowBase + r) * 256 + col] = f2bf(v);
            }
        } else {
            const float bv = bias[col];
            u16* out = (u16*)outp;
            #pragma unroll
            for (int r = 0; r < 4; ++r) {
                const int m = rowBase + r;
                const float v = acc[r] + bv;
                const size_t off = (m < brows)
                    ? ((size_t)m * 256 + col)                    // cur half
                    : ((size_t)(m - brows) * 256 + 128 + col);   // prev half
                out[off] = f2bf(v);
            }
        }
    }
}

// ---------------------------------------------------------------------------
extern "C" void kernel_launch(void* const* d_in, const int* in_sizes, int n_in,
                              void* d_out, int out_size, void* d_ws, size_t ws_size,
                              hipStream_t stream)
{
    const int*   diag  = (const int*)d_in[0];
    const int*   proc  = (const int*)d_in[1];
    const int*   pdiag = (const int*)d_in[2];
    const int*   pproc = (const int*)d_in[3];
    const float* demb  = (const float*)d_in[4];
    const float* pemb  = (const float*)d_in[5];
    const float* W1    = (const float*)d_in[6];
    const float* b1    = (const float*)d_in[7];
    const float* W2    = (const float*)d_in[8];
    const float* b2    = (const float*)d_in[9];
    const float* W3    = (const float*)d_in[10];
    const float* b3    = (const float*)d_in[11];

    char* ws = (char*)d_ws;
    // ws layout (bytes):
    //   X   [16384,256] bf16 : 0        .. 8388608
    //   Xp  [16384,256] bf16 : 8388608  .. 16777216   (contiguous after X -> stacked A for GEMM1)
    //   rep [16384,256] bf16 : 16777216 .. 25165824
    //   h   [16384,256] bf16 : 25165824 .. 33554432
    //   W1b [128,256]   bf16 : 33554432
    //   W2b [256,256]   bf16 : 33619968
    //   W3b [1024,256]  bf16 : 33751040 .. 34275328
    u16* X   = (u16*)ws;
    u16* Xp  = X + (size_t)NB * 256;
    u16* rep = (u16*)(ws + 16777216);
    u16* h   = (u16*)(ws + 25165824);
    u16* W1b = (u16*)(ws + 33554432);
    u16* W2b = (u16*)(ws + 33619968);
    u16* W3b = (u16*)(ws + 33751040);

    convert_kernel<<<1408, 256, 0, stream>>>(W1, W2, W3, W1b, W2b, W3b);
    gather_kernel<<<NB / 2, 256, 0, stream>>>(diag, proc, pdiag, pproc, demb, pemb, X, Xp);
    // GEMM1: stacked [X;Xp] (M=32768) x W1[128,256] -> rep (cur|prev mapping)
    gemm_bt<0><<<dim3(512, 2), 256, 0, stream>>>(X, W1b, b1, rep, NB);
    // GEMM2: rep x W2[256,256] + relu -> h
    gemm_bt<1><<<dim3(256, 4), 256, 0, stream>>>(rep, W2b, b2, h, 0);
    // GEMM3: h x W3[1024(pad),256] + sigmoid -> out fp32 [16384,1000]
    gemm_bt<2><<<dim3(256, 16), 256, 0, stream>>>(h, W3b, b3, d_out, 0);
}

// Round 2
// 300.031 us; speedup vs baseline: 1.2891x; 1.2891x over previous
//
#include <hip/hip_runtime.h>
#include <hip/hip_bf16.h>
#include <math.h>

#define NB 16384
#define MED 1000
#define MD 100000          // diag table rows
#define MP 50000           // proc table rows
#define TDBLK 782          // ceil(100000/128)
#define TPBLK 391          // ceil(50000/128)

typedef __bf16 bf16x8 __attribute__((ext_vector_type(8)));
typedef float  f32x4  __attribute__((ext_vector_type(4)));
typedef unsigned short u16;
typedef unsigned int   u32;

__device__ __forceinline__ u16 f2bf(float f) {
    union { float f; u32 u; } v; v.f = f;
    u32 r = v.u + 0x7fffu + ((v.u >> 16) & 1u);   // RNE
    return (u16)(r >> 16);
}
__device__ __forceinline__ float bflo(u32 u) { union { u32 u; float f; } v; v.u = u << 16;          return v.f; }
__device__ __forceinline__ float bfhi(u32 u) { union { u32 u; float f; } v; v.u = u & 0xffff0000u; return v.f; }

// ---------------------------------------------------------------------------
// fp32 -> bf16 weight conversion: W1 (32768), W2 (65536), W3 (padded 262144)
// ---------------------------------------------------------------------------
__global__ __launch_bounds__(256) void convert_kernel(
    const float* __restrict__ W1, const float* __restrict__ W2,
    const float* __restrict__ W3,
    u16* __restrict__ W1b, u16* __restrict__ W2b, u16* __restrict__ W3b)
{
    int i = blockIdx.x * 256 + threadIdx.x;
    if (i < 32768) { W1b[i] = f2bf(W1[i]); return; }
    i -= 32768;
    if (i < 65536) { W2b[i] = f2bf(W2[i]); return; }
    i -= 65536;
    if (i < 262144) W3b[i] = (i < MED * 256) ? f2bf(W3[i]) : (u16)0;
}

// ---------------------------------------------------------------------------
// Table transform: T_d = E_d @ W1[:, :128]^T,  T_p = E_p @ W1[:, 128:]^T
// (linearity of EmbeddingBag-sum through Linear -> GEMM1 eliminated).
// A fp32 [M,128] (cvt to bf16 in-reg), B = W1b rows at koff, K=128, N=128.
// Block: 4 waves, tile M=128 (wave 32) x N=128. Output bf16 row-major.
// ---------------------------------------------------------------------------
__global__ __launch_bounds__(256) void transform_kernel(
    const float* __restrict__ Ed, const float* __restrict__ Ep,
    const u16* __restrict__ W1b, u16* __restrict__ Td, u16* __restrict__ Tp)
{
    int blk = blockIdx.x;
    const float* E; u16* T; int M, koff;
    if (blk < TDBLK) { E = Ed; T = Td; M = MD; koff = 0; }
    else             { blk -= TDBLK; E = Ep; T = Tp; M = MP; koff = 128; }

    const int wave = threadIdx.x >> 6, lane = threadIdx.x & 63;
    const int quad = lane >> 4, l16 = lane & 15;
    const int m0 = blk * 128 + wave * 32 + l16;
    const float* aP0 = E + (size_t)min(m0,      M - 1) * 128 + quad * 8;
    const float* aP1 = E + (size_t)min(m0 + 16, M - 1) * 128 + quad * 8;
    const u16*   wP  = W1b + (size_t)l16 * 256 + koff + quad * 8;

    f32x4 acc[2][8];
    #pragma unroll
    for (int mt = 0; mt < 2; ++mt)
        #pragma unroll
        for (int nt = 0; nt < 8; ++nt) acc[mt][nt] = (f32x4){0.f, 0.f, 0.f, 0.f};

    #pragma unroll
    for (int ks = 0; ks < 4; ++ks) {
        union { bf16x8 v; u16 s[8]; } a0, a1;
        const float4 f0 = *(const float4*)(aP0 + ks * 32);
        const float4 f1 = *(const float4*)(aP0 + ks * 32 + 4);
        const float4 g0 = *(const float4*)(aP1 + ks * 32);
        const float4 g1 = *(const float4*)(aP1 + ks * 32 + 4);
        a0.s[0]=f2bf(f0.x); a0.s[1]=f2bf(f0.y); a0.s[2]=f2bf(f0.z); a0.s[3]=f2bf(f0.w);
        a0.s[4]=f2bf(f1.x); a0.s[5]=f2bf(f1.y); a0.s[6]=f2bf(f1.z); a0.s[7]=f2bf(f1.w);
        a1.s[0]=f2bf(g0.x); a1.s[1]=f2bf(g0.y); a1.s[2]=f2bf(g0.z); a1.s[3]=f2bf(g0.w);
        a1.s[4]=f2bf(g1.x); a1.s[5]=f2bf(g1.y); a1.s[6]=f2bf(g1.z); a1.s[7]=f2bf(g1.w);
        #pragma unroll
        for (int nt = 0; nt < 8; ++nt) {
            const bf16x8 b = *(const bf16x8*)(wP + nt * 16 * 256 + ks * 32);
            acc[0][nt] = __builtin_amdgcn_mfma_f32_16x16x32_bf16(a0.v, b, acc[0][nt], 0, 0, 0);
            acc[1][nt] = __builtin_amdgcn_mfma_f32_16x16x32_bf16(a1.v, b, acc[1][nt], 0, 0, 0);
        }
    }

    #pragma unroll
    for (int mt = 0; mt < 2; ++mt) {
        const int rb = blk * 128 + wave * 32 + mt * 16 + quad * 4;
        #pragma unroll
        for (int nt = 0; nt < 8; ++nt) {
            const int col = nt * 16 + l16;
            #pragma unroll
            for (int r = 0; r < 4; ++r) {
                const int row = rb + r;
                if (row < M) T[(size_t)row * 128 + col] = f2bf(acc[mt][nt][r]);
            }
        }
    }
}

// ---------------------------------------------------------------------------
// Gather+sum from transformed tables -> rep directly (cur|prev, +b1 folded).
// Block = 4 batch rows. t = sub(2b)*64 | bag(2b)*16 | lc(4b).
// Each thread: 16 B (8 bf16 cols) x 32 rows, 8-deep load batches.
// bag0+bag1 -> rep[b,0:128]; bag2+bag3 -> rep[b,128:256] (combine via LDS).
// ---------------------------------------------------------------------------
__global__ __launch_bounds__(256) void gather_rep(
    const int* __restrict__ diag, const int* __restrict__ proc,
    const int* __restrict__ pdiag, const int* __restrict__ pproc,
    const u16* __restrict__ Td, const u16* __restrict__ Tp,
    const float* __restrict__ b1, u16* __restrict__ rep)
{
    __shared__ int   sidx[528];          // [sub][bag][32] padded: sub*132+bag*33+l
    __shared__ float sred[128][8];
    const int t = threadIdx.x;

    for (int i = t; i < 512; i += 256) {
        const int s = i >> 7, bg = (i >> 5) & 3, l = i & 31;
        const int* cp = (bg == 0) ? diag : (bg == 1) ? proc : (bg == 2) ? pdiag : pproc;
        sidx[s * 132 + bg * 33 + l] = cp[(blockIdx.x * 4 + s) * 32 + l];
    }
    __syncthreads();

    const int sub = t >> 6, bag = (t >> 4) & 3, lc = t & 15;
    const u16* tbl = (bag & 1) ? Tp : Td;
    const int* myidx = &sidx[sub * 132 + bag * 33];

    float s0=0,s1=0,s2=0,s3=0,s4=0,s5=0,s6=0,s7=0;
    #pragma unroll
    for (int g = 0; g < 4; ++g) {
        uint4 v[8];
        #pragma unroll
        for (int j = 0; j < 8; ++j)
            v[j] = *(const uint4*)(tbl + (size_t)myidx[g * 8 + j] * 128 + lc * 8);
        #pragma unroll
        for (int j = 0; j < 8; ++j) {
            s0 += bflo(v[j].x); s1 += bfhi(v[j].x);
            s2 += bflo(v[j].y); s3 += bfhi(v[j].y);
            s4 += bflo(v[j].z); s5 += bfhi(v[j].z);
            s6 += bflo(v[j].w); s7 += bfhi(v[j].w);
        }
    }

    const int oid = sub * 32 + (bag >> 1) * 16 + lc;
    if (bag & 1) {
        *(float4*)&sred[oid][0] = make_float4(s0, s1, s2, s3);
        *(float4*)&sred[oid][4] = make_float4(s4, s5, s6, s7);
    }
    __syncthreads();
    if (!(bag & 1)) {
        const float4 p0 = *(const float4*)&sred[oid][0];
        const float4 p1 = *(const float4*)&sred[oid][4];
        const float4 c0 = *(const float4*)(b1 + lc * 8);
        const float4 c1 = *(const float4*)(b1 + lc * 8 + 4);
        s0 += p0.x + c0.x; s1 += p0.y + c0.y; s2 += p0.z + c0.z; s3 += p0.w + c0.w;
        s4 += p1.x + c1.x; s5 += p1.y + c1.y; s6 += p1.z + c1.z; s7 += p1.w + c1.w;
        uint4 o;
        o.x = (u32)f2bf(s0) | ((u32)f2bf(s1) << 16);
        o.y = (u32)f2bf(s2) | ((u32)f2bf(s3) << 16);
        o.z = (u32)f2bf(s4) | ((u32)f2bf(s5) << 16);
        o.w = (u32)f2bf(s6) | ((u32)f2bf(s7) << 16);
        const int b = blockIdx.x * 4 + sub;
        *(uint4*)(rep + (size_t)b * 256 + (bag >> 1) * 128 + lc * 8) = o;
    }
}

// ---------------------------------------------------------------------------
// TN GEMM, K=256, bf16 MFMA 16x16x32. Block tile M=128 (4 waves x 32) x N=64.
// Wave tile 32x64: 8 MFMA : 6 x 16B loads per K-step.
// EPI 1: +bias, relu, bf16 [M,256].  EPI 2: +bias, sigmoid, fp32 [M,1000].
// ---------------------------------------------------------------------------
template<int EPI>
__global__ __launch_bounds__(256) void gemm_bt(
    const u16* __restrict__ A, const u16* __restrict__ W,
    const float* __restrict__ bias, void* __restrict__ outp)
{
    const int wave = threadIdx.x >> 6, lane = threadIdx.x & 63;
    const int quad = lane >> 4, l16 = lane & 15;
    const int mBase = blockIdx.x * 128 + wave * 32;
    const int nBase = blockIdx.y * 64;
    const u16* aP0 = A + (size_t)(mBase + l16) * 256 + quad * 8;
    const u16* aP1 = aP0 + 16 * 256;
    const u16* wP  = W + (size_t)(nBase + l16) * 256 + quad * 8;

    f32x4 acc[2][4];
    #pragma unroll
    for (int mt = 0; mt < 2; ++mt)
        #pragma unroll
        for (int nt = 0; nt < 4; ++nt) acc[mt][nt] = (f32x4){0.f, 0.f, 0.f, 0.f};

    #pragma unroll
    for (int ks = 0; ks < 8; ++ks) {
        const bf16x8 a0 = *(const bf16x8*)(aP0 + ks * 32);
        const bf16x8 a1 = *(const bf16x8*)(aP1 + ks * 32);
        #pragma unroll
        for (int nt = 0; nt < 4; ++nt) {
            const bf16x8 b = *(const bf16x8*)(wP + nt * 16 * 256 + ks * 32);
            acc[0][nt] = __builtin_amdgcn_mfma_f32_16x16x32_bf16(a0, b, acc[0][nt], 0, 0, 0);
            acc[1][nt] = __builtin_amdgcn_mfma_f32_16x16x32_bf16(a1, b, acc[1][nt], 0, 0, 0);
        }
    }

    #pragma unroll
    for (int mt = 0; mt < 2; ++mt) {
        const int rowB = mBase + mt * 16 + quad * 4;
        #pragma unroll
        for (int nt = 0; nt < 4; ++nt) {
            const int col = nBase + nt * 16 + l16;
            if (EPI == 2) {
                if (col < MED) {
                    const float bv = bias[col];
                    float* out = (float*)outp;
                    #pragma unroll
                    for (int r = 0; r < 4; ++r) {
                        const float v = acc[mt][nt][r] + bv;
                        out[(size_t)(rowB + r) * MED + col] = 1.0f / (1.0f + __expf(-v));
                    }
                }
            } else {
                const float bv = bias[col];
                u16* out = (u16*)outp;
                #pragma unroll
                for (int r = 0; r < 4; ++r) {
                    float v = acc[mt][nt][r] + bv;
                    v = v > 0.f ? v : 0.f;
                    out[(size_t)(rowB + r) * 256 + col] = f2bf(v);
                }
            }
        }
    }
}

// ---------------------------------------------------------------------------
extern "C" void kernel_launch(void* const* d_in, const int* in_sizes, int n_in,
                              void* d_out, int out_size, void* d_ws, size_t ws_size,
                              hipStream_t stream)
{
    const int*   diag  = (const int*)d_in[0];
    const int*   proc  = (const int*)d_in[1];
    const int*   pdiag = (const int*)d_in[2];
    const int*   pproc = (const int*)d_in[3];
    const float* demb  = (const float*)d_in[4];
    const float* pemb  = (const float*)d_in[5];
    const float* W1    = (const float*)d_in[6];
    const float* b1    = (const float*)d_in[7];
    const float* W2    = (const float*)d_in[8];
    const float* b2    = (const float*)d_in[9];
    const float* W3    = (const float*)d_in[10];
    const float* b3    = (const float*)d_in[11];

    char* ws = (char*)d_ws;
    // ws layout (bytes), total 47,509,504:
    //   Td  [100000,128] bf16 : 0          .. 25,600,000
    //   Tp  [ 50000,128] bf16 : 25,600,000 .. 38,400,000
    //   rep [16384,256]  bf16 : 38,400,000 .. 46,788,608
    //   W1b/W2b/W3b(pad 1024) : 46,788,608 .. 47,509,504
    //   h aliases Td (Td dead after gather_rep)
    u16* Td  = (u16*)ws;
    u16* Tp  = (u16*)(ws + 25600000);
    u16* rep = (u16*)(ws + 38400000);
    u16* W1b = (u16*)(ws + 46788608);
    u16* W2b = (u16*)(ws + 46854144);
    u16* W3b = (u16*)(ws + 46985216);
    u16* h   = (u16*)ws;

    convert_kernel<<<1408, 256, 0, stream>>>(W1, W2, W3, W1b, W2b, W3b);
    transform_kernel<<<TDBLK + TPBLK, 256, 0, stream>>>(demb, pemb, W1b, Td, Tp);
    gather_rep<<<NB / 4, 256, 0, stream>>>(diag, proc, pdiag, pproc, Td, Tp, b1, rep);
    gemm_bt<1><<<dim3(128, 4), 256, 0, stream>>>(rep, W2b, b2, h);
    gemm_bt<2><<<dim3(128, 16), 256, 0, stream>>>(h, W3b, b3, d_out);
}

// Round 3
// 293.584 us; speedup vs baseline: 1.3174x; 1.0220x over previous
//
#include <hip/hip_runtime.h>
#include <hip/hip_bf16.h>
#include <math.h>

#define NB 16384
#define MED 1000
#define MD 100000          // diag table rows
#define MP 50000           // proc table rows
#define TDBLK 782          // ceil(100000/128)
#define TPBLK 391          // ceil(50000/128)

typedef __bf16 bf16x8 __attribute__((ext_vector_type(8)));
typedef float  f32x4  __attribute__((ext_vector_type(4)));
typedef unsigned short u16;
typedef unsigned int   u32;

__device__ __forceinline__ u16 f2bf(float f) {
    union { float f; u32 u; } v; v.f = f;
    u32 r = v.u + 0x7fffu + ((v.u >> 16) & 1u);   // RNE
    return (u16)(r >> 16);
}
__device__ __forceinline__ float bflo(u32 u) { union { u32 u; float f; } v; v.u = u << 16;          return v.f; }
__device__ __forceinline__ float bfhi(u32 u) { union { u32 u; float f; } v; v.u = u & 0xffff0000u; return v.f; }

// ---------------------------------------------------------------------------
// fp32 -> bf16 weight conversion: W1 (32768), W2 (65536), W3 (padded 262144)
// ---------------------------------------------------------------------------
__global__ __launch_bounds__(256) void convert_kernel(
    const float* __restrict__ W1, const float* __restrict__ W2,
    const float* __restrict__ W3,
    u16* __restrict__ W1b, u16* __restrict__ W2b, u16* __restrict__ W3b)
{
    int i = blockIdx.x * 256 + threadIdx.x;
    if (i < 32768) { W1b[i] = f2bf(W1[i]); return; }
    i -= 32768;
    if (i < 65536) { W2b[i] = f2bf(W2[i]); return; }
    i -= 65536;
    if (i < 262144) W3b[i] = (i < MED * 256) ? f2bf(W3[i]) : (u16)0;
}

// ---------------------------------------------------------------------------
// Table transform: T_d = E_d @ W1[:, :128]^T,  T_p = E_p @ W1[:, 128:]^T
// (GEMM1 eliminated by linearity of bag-sum through Linear).
// ---------------------------------------------------------------------------
__global__ __launch_bounds__(256) void transform_kernel(
    const float* __restrict__ Ed, const float* __restrict__ Ep,
    const u16* __restrict__ W1b, u16* __restrict__ Td, u16* __restrict__ Tp)
{
    int blk = blockIdx.x;
    const float* E; u16* T; int M, koff;
    if (blk < TDBLK) { E = Ed; T = Td; M = MD; koff = 0; }
    else             { blk -= TDBLK; E = Ep; T = Tp; M = MP; koff = 128; }

    const int wave = threadIdx.x >> 6, lane = threadIdx.x & 63;
    const int quad = lane >> 4, l16 = lane & 15;
    const int m0 = blk * 128 + wave * 32 + l16;
    const float* aP0 = E + (size_t)min(m0,      M - 1) * 128 + quad * 8;
    const float* aP1 = E + (size_t)min(m0 + 16, M - 1) * 128 + quad * 8;
    const u16*   wP  = W1b + (size_t)l16 * 256 + koff + quad * 8;

    f32x4 acc[2][8];
    #pragma unroll
    for (int mt = 0; mt < 2; ++mt)
        #pragma unroll
        for (int nt = 0; nt < 8; ++nt) acc[mt][nt] = (f32x4){0.f, 0.f, 0.f, 0.f};

    #pragma unroll
    for (int ks = 0; ks < 4; ++ks) {
        union { bf16x8 v; u16 s[8]; } a0, a1;
        const float4 f0 = *(const float4*)(aP0 + ks * 32);
        const float4 f1 = *(const float4*)(aP0 + ks * 32 + 4);
        const float4 g0 = *(const float4*)(aP1 + ks * 32);
        const float4 g1 = *(const float4*)(aP1 + ks * 32 + 4);
        a0.s[0]=f2bf(f0.x); a0.s[1]=f2bf(f0.y); a0.s[2]=f2bf(f0.z); a0.s[3]=f2bf(f0.w);
        a0.s[4]=f2bf(f1.x); a0.s[5]=f2bf(f1.y); a0.s[6]=f2bf(f1.z); a0.s[7]=f2bf(f1.w);
        a1.s[0]=f2bf(g0.x); a1.s[1]=f2bf(g0.y); a1.s[2]=f2bf(g0.z); a1.s[3]=f2bf(g0.w);
        a1.s[4]=f2bf(g1.x); a1.s[5]=f2bf(g1.y); a1.s[6]=f2bf(g1.z); a1.s[7]=f2bf(g1.w);
        #pragma unroll
        for (int nt = 0; nt < 8; ++nt) {
            const bf16x8 b = *(const bf16x8*)(wP + nt * 16 * 256 + ks * 32);
            acc[0][nt] = __builtin_amdgcn_mfma_f32_16x16x32_bf16(a0.v, b, acc[0][nt], 0, 0, 0);
            acc[1][nt] = __builtin_amdgcn_mfma_f32_16x16x32_bf16(a1.v, b, acc[1][nt], 0, 0, 0);
        }
    }

    #pragma unroll
    for (int mt = 0; mt < 2; ++mt) {
        const int rb = blk * 128 + wave * 32 + mt * 16 + quad * 4;
        #pragma unroll
        for (int nt = 0; nt < 8; ++nt) {
            const int col = nt * 16 + l16;
            #pragma unroll
            for (int r = 0; r < 4; ++r) {
                const int row = rb + r;
                if (row < M) T[(size_t)row * 128 + col] = f2bf(acc[mt][nt][r]);
            }
        }
    }
}

// ---------------------------------------------------------------------------
// Gather+sum from transformed tables -> rep (cur|prev, +b1 folded).
// Block = 4 batch rows; thread = 16 B x 32 rows. Ping-pong 8-deep load
// batches (16 uint4 in flight) to raise fabric utilization.
// ---------------------------------------------------------------------------
__global__ __launch_bounds__(256) void gather_rep(
    const int* __restrict__ diag, const int* __restrict__ proc,
    const int* __restrict__ pdiag, const int* __restrict__ pproc,
    const u16* __restrict__ Td, const u16* __restrict__ Tp,
    const float* __restrict__ b1, u16* __restrict__ rep)
{
    __shared__ int   sidx[528];          // [sub][bag][32] padded
    __shared__ float sred[128][8];
    const int t = threadIdx.x;

    for (int i = t; i < 512; i += 256) {
        const int s = i >> 7, bg = (i >> 5) & 3, l = i & 31;
        const int* cp = (bg == 0) ? diag : (bg == 1) ? proc : (bg == 2) ? pdiag : pproc;
        sidx[s * 132 + bg * 33 + l] = cp[(blockIdx.x * 4 + s) * 32 + l];
    }
    __syncthreads();

    const int sub = t >> 6, bag = (t >> 4) & 3, lc = t & 15;
    const u16* tbl = (bag & 1) ? Tp : Td;
    const int* myidx = &sidx[sub * 132 + bag * 33];

    float s0=0,s1=0,s2=0,s3=0,s4=0,s5=0,s6=0,s7=0;
    uint4 va[8], vb[8];
    #pragma unroll
    for (int j = 0; j < 8; ++j)
        va[j] = *(const uint4*)(tbl + (size_t)myidx[j] * 128 + lc * 8);
    #pragma unroll
    for (int j = 0; j < 8; ++j)
        vb[j] = *(const uint4*)(tbl + (size_t)myidx[8 + j] * 128 + lc * 8);

#define CONSUME(V) do { \
    _Pragma("unroll") \
    for (int j = 0; j < 8; ++j) { \
        s0 += bflo(V[j].x); s1 += bfhi(V[j].x); \
        s2 += bflo(V[j].y); s3 += bfhi(V[j].y); \
        s4 += bflo(V[j].z); s5 += bfhi(V[j].z); \
        s6 += bflo(V[j].w); s7 += bfhi(V[j].w); \
    } } while (0)

    {   // prefetch g=2 while consuming g=0, etc.
        uint4 tmp[8];
        #pragma unroll
        for (int j = 0; j < 8; ++j)
            tmp[j] = *(const uint4*)(tbl + (size_t)myidx[16 + j] * 128 + lc * 8);
        CONSUME(va);
        #pragma unroll
        for (int j = 0; j < 8; ++j) va[j] = tmp[j];
    }
    {
        uint4 tmp[8];
        #pragma unroll
        for (int j = 0; j < 8; ++j)
            tmp[j] = *(const uint4*)(tbl + (size_t)myidx[24 + j] * 128 + lc * 8);
        CONSUME(vb);
        #pragma unroll
        for (int j = 0; j < 8; ++j) vb[j] = tmp[j];
    }
    CONSUME(va);
    CONSUME(vb);
#undef CONSUME

    const int oid = sub * 32 + (bag >> 1) * 16 + lc;
    if (bag & 1) {
        *(float4*)&sred[oid][0] = make_float4(s0, s1, s2, s3);
        *(float4*)&sred[oid][4] = make_float4(s4, s5, s6, s7);
    }
    __syncthreads();
    if (!(bag & 1)) {
        const float4 p0 = *(const float4*)&sred[oid][0];
        const float4 p1 = *(const float4*)&sred[oid][4];
        const float4 c0 = *(const float4*)(b1 + lc * 8);
        const float4 c1 = *(const float4*)(b1 + lc * 8 + 4);
        s0 += p0.x + c0.x; s1 += p0.y + c0.y; s2 += p0.z + c0.z; s3 += p0.w + c0.w;
        s4 += p1.x + c1.x; s5 += p1.y + c1.y; s6 += p1.z + c1.z; s7 += p1.w + c1.w;
        uint4 o;
        o.x = (u32)f2bf(s0) | ((u32)f2bf(s1) << 16);
        o.y = (u32)f2bf(s2) | ((u32)f2bf(s3) << 16);
        o.z = (u32)f2bf(s4) | ((u32)f2bf(s5) << 16);
        o.w = (u32)f2bf(s6) | ((u32)f2bf(s7) << 16);
        const int b = blockIdx.x * 4 + sub;
        *(uint4*)(rep + (size_t)b * 256 + (bag >> 1) * 128 + lc * 8) = o;
    }
}

// ---------------------------------------------------------------------------
// Fused GEMM2+GEMM3. Block = 32-row M-tile (grid 512 -> 2 blocks/CU).
// Phase 1: h[32,256] = relu(rep @ W2^T + b2) -> LDS bf16 (stride 264).
//   4 waves: wave w does rows (w&1)*16..+16, cols (w>>1)*128 (8 n-tiles).
// Phase 2: out[32,1000] = sigmoid(h @ W3^T + b3), W3 padded to 1024 rows.
//   Wave w covers cols w*256..+256 in 4 chunks of 64; a-frags from LDS.
// ---------------------------------------------------------------------------
__global__ __launch_bounds__(256) void gemm23(
    const u16* __restrict__ rep, const u16* __restrict__ W2b,
    const float* __restrict__ b2, const u16* __restrict__ W3b,
    const float* __restrict__ b3, float* __restrict__ out)
{
    __shared__ u16 hs[32][264];
    const int wave = threadIdx.x >> 6, lane = threadIdx.x & 63;
    const int quad = lane >> 4, l16 = lane & 15;
    const int mBase = blockIdx.x * 32;

    // ---- phase 1 ----
    {
        const int mrow = mBase + (wave & 1) * 16 + l16;
        const int ncol0 = (wave >> 1) * 128;
        const u16* aP = rep + (size_t)mrow * 256 + quad * 8;
        bf16x8 a[8];
        #pragma unroll
        for (int ks = 0; ks < 8; ++ks) a[ks] = *(const bf16x8*)(aP + ks * 32);

        #pragma unroll
        for (int nt = 0; nt < 8; ++nt) {
            const int col = ncol0 + nt * 16 + l16;
            const u16* wP = W2b + (size_t)col * 256 + quad * 8;
            f32x4 acc = {0.f, 0.f, 0.f, 0.f};
            #pragma unroll
            for (int ks = 0; ks < 8; ++ks) {
                const bf16x8 b = *(const bf16x8*)(wP + ks * 32);
                acc = __builtin_amdgcn_mfma_f32_16x16x32_bf16(a[ks], b, acc, 0, 0, 0);
            }
            const float bv = b2[col];
            #pragma unroll
            for (int r = 0; r < 4; ++r) {
                float v = acc[r] + bv;
                v = v > 0.f ? v : 0.f;
                hs[(wave & 1) * 16 + quad * 4 + r][col] = f2bf(v);
            }
        }
    }
    __syncthreads();

    // ---- phase 2 ----
    const int colW = wave * 256;
    #pragma unroll
    for (int nc = 0; nc < 4; ++nc) {
        f32x4 acc[2][4];
        #pragma unroll
        for (int mt = 0; mt < 2; ++mt)
            #pragma unroll
            for (int nti = 0; nti < 4; ++nti) acc[mt][nti] = (f32x4){0.f,0.f,0.f,0.f};

        #pragma unroll
        for (int ks = 0; ks < 8; ++ks) {
            bf16x8 af[2];
            #pragma unroll
            for (int mt = 0; mt < 2; ++mt)
                af[mt] = *(const bf16x8*)&hs[mt * 16 + l16][quad * 8 + ks * 32];
            #pragma unroll
            for (int nti = 0; nti < 4; ++nti) {
                const int wrow = colW + nc * 64 + nti * 16 + l16;
                const bf16x8 b = *(const bf16x8*)(W3b + (size_t)wrow * 256 + quad * 8 + ks * 32);
                acc[0][nti] = __builtin_amdgcn_mfma_f32_16x16x32_bf16(af[0], b, acc[0][nti], 0, 0, 0);
                acc[1][nti] = __builtin_amdgcn_mfma_f32_16x16x32_bf16(af[1], b, acc[1][nti], 0, 0, 0);
            }
        }
        #pragma unroll
        for (int nti = 0; nti < 4; ++nti) {
            const int col = colW + nc * 64 + nti * 16 + l16;
            if (col < MED) {
                const float bv = b3[col];
                #pragma unroll
                for (int mt = 0; mt < 2; ++mt) {
                    #pragma unroll
                    for (int r = 0; r < 4; ++r) {
                        const float v = acc[mt][nti][r] + bv;
                        out[(size_t)(mBase + mt * 16 + quad * 4 + r) * MED + col] =
                            1.0f / (1.0f + __expf(-v));
                    }
                }
            }
        }
    }
}

// ---------------------------------------------------------------------------
extern "C" void kernel_launch(void* const* d_in, const int* in_sizes, int n_in,
                              void* d_out, int out_size, void* d_ws, size_t ws_size,
                              hipStream_t stream)
{
    const int*   diag  = (const int*)d_in[0];
    const int*   proc  = (const int*)d_in[1];
    const int*   pdiag = (const int*)d_in[2];
    const int*   pproc = (const int*)d_in[3];
    const float* demb  = (const float*)d_in[4];
    const float* pemb  = (const float*)d_in[5];
    const float* W1    = (const float*)d_in[6];
    const float* b1    = (const float*)d_in[7];
    const float* W2    = (const float*)d_in[8];
    const float* b2    = (const float*)d_in[9];
    const float* W3    = (const float*)d_in[10];
    const float* b3    = (const float*)d_in[11];

    char* ws = (char*)d_ws;
    // ws layout (bytes), total ~47.5 MB:
    //   Td  [100000,128] bf16 : 0          .. 25,600,000
    //   Tp  [ 50000,128] bf16 : 25,600,000 .. 38,400,000
    //   rep [16384,256]  bf16 : 38,400,000 .. 46,788,608
    //   W1b/W2b/W3b(pad 1024) : 46,788,608 .. 47,509,504
    u16* Td  = (u16*)ws;
    u16* Tp  = (u16*)(ws + 25600000);
    u16* rep = (u16*)(ws + 38400000);
    u16* W1b = (u16*)(ws + 46788608);
    u16* W2b = (u16*)(ws + 46854144);
    u16* W3b = (u16*)(ws + 46985216);

    convert_kernel<<<1408, 256, 0, stream>>>(W1, W2, W3, W1b, W2b, W3b);
    transform_kernel<<<TDBLK + TPBLK, 256, 0, stream>>>(demb, pemb, W1b, Td, Tp);
    gather_rep<<<NB / 4, 256, 0, stream>>>(diag, proc, pdiag, pproc, Td, Tp, b1, rep);
    gemm23<<<512, 256, 0, stream>>>(rep, W2b, b2, W3b, b3, (float*)d_out);
}

// Round 4
// 247.050 us; speedup vs baseline: 1.5656x; 1.1884x over previous
//
#include <hip/hip_runtime.h>
#include <hip/hip_bf16.h>
#include <math.h>

#define NB 16384
#define MED 1000
#define MD 100000          // diag table rows
#define MP 50000           // proc table rows
#define TDBLK 782          // ceil(100000/128)
#define TPBLK 391          // ceil(50000/128)
#define NTR (TDBLK + TPBLK)
#define NCV 1280           // convert blocks: (65536+262144)/256
#define FP8_SCALE 4096.0f
#define FP8_INV   (1.0f / 4096.0f)

typedef __bf16 bf16x8 __attribute__((ext_vector_type(8)));
typedef float  f32x4  __attribute__((ext_vector_type(4)));
typedef float  f32x2  __attribute__((ext_vector_type(2)));
typedef unsigned short u16;
typedef unsigned int   u32;
typedef unsigned char  u8;

__device__ __forceinline__ u16 f2bf(float f) {
    union { float f; u32 u; } v; v.f = f;
    u32 r = v.u + 0x7fffu + ((v.u >> 16) & 1u);   // RNE
    return (u16)(r >> 16);
}

// ---------------------------------------------------------------------------
// prep: (a) transform tables  T_d = fp8( E_d @ W1[:, :128]^T * 4096 ),
//                             T_p = fp8( E_p @ W1[:, 128:]^T * 4096 )
//       (b) convert W2, W3 -> bf16 (W3 zero-padded to 1024 rows)
// Transform blocks: 128 table rows each. MFMA operands swapped vs R3:
//   A = W1 rows (out-channels, staged bf16 in LDS), B = E rows.
//   C/D: n(col)=lane&15 -> table row, m(row)=quad*4+reg -> 4 CONSECUTIVE
//   out-cols per lane -> one packed fp8 dword store per (mt, row).
// ---------------------------------------------------------------------------
__global__ __launch_bounds__(256) void prep_kernel(
    const float* __restrict__ Ed, const float* __restrict__ Ep,
    const float* __restrict__ W1,
    const float* __restrict__ W2, const float* __restrict__ W3,
    u8* __restrict__ Td, u8* __restrict__ Tp,
    u16* __restrict__ W2b, u16* __restrict__ W3b)
{
    __shared__ u16 w1s[128 * 132];     // [out 128][k 128] bf16, stride 132
    const int bid = blockIdx.x, tid = threadIdx.x;

    if (bid >= NTR) {                   // ---- weight convert blocks ----
        int i = (bid - NTR) * 256 + tid;
        if (i < 65536) { W2b[i] = f2bf(W2[i]); return; }
        i -= 65536;
        if (i < 262144) W3b[i] = (i < MED * 256) ? f2bf(W3[i]) : (u16)0;
        return;
    }

    int blk = bid;
    const float* E; u8* T; int M, koff;
    if (blk < TDBLK) { E = Ed; T = Td; M = MD; koff = 0; }
    else             { blk -= TDBLK; E = Ep; T = Tp; M = MP; koff = 128; }

    // stage W1[:, koff:koff+128] bf16 into LDS
    for (int idx = tid; idx < 4096; idx += 256) {     // 4096 float4s
        const int row = idx >> 5, c4 = idx & 31;
        const float4 v = *(const float4*)(W1 + row * 256 + koff + c4 * 4);
        u16* d = &w1s[row * 132 + c4 * 4];
        d[0] = f2bf(v.x); d[1] = f2bf(v.y); d[2] = f2bf(v.z); d[3] = f2bf(v.w);
    }
    __syncthreads();

    const int wave = tid >> 6, lane = tid & 63;
    const int quad = lane >> 4, l16 = lane & 15;
    const int n0 = blk * 128 + wave * 32;
    const float* bP0 = E + (size_t)min(n0 + l16,      M - 1) * 128 + quad * 8;
    const float* bP1 = E + (size_t)min(n0 + 16 + l16, M - 1) * 128 + quad * 8;

    f32x4 acc[8][2];
    #pragma unroll
    for (int mt = 0; mt < 8; ++mt) {
        acc[mt][0] = (f32x4){0.f,0.f,0.f,0.f};
        acc[mt][1] = (f32x4){0.f,0.f,0.f,0.f};
    }

    #pragma unroll
    for (int ks = 0; ks < 4; ++ks) {
        union { bf16x8 v; u16 s[8]; } b0, b1;
        const float4 f0 = *(const float4*)(bP0 + ks * 32);
        const float4 f1 = *(const float4*)(bP0 + ks * 32 + 4);
        const float4 g0 = *(const float4*)(bP1 + ks * 32);
        const float4 g1 = *(const float4*)(bP1 + ks * 32 + 4);
        b0.s[0]=f2bf(f0.x); b0.s[1]=f2bf(f0.y); b0.s[2]=f2bf(f0.z); b0.s[3]=f2bf(f0.w);
        b0.s[4]=f2bf(f1.x); b0.s[5]=f2bf(f1.y); b0.s[6]=f2bf(f1.z); b0.s[7]=f2bf(f1.w);
        b1.s[0]=f2bf(g0.x); b1.s[1]=f2bf(g0.y); b1.s[2]=f2bf(g0.z); b1.s[3]=f2bf(g0.w);
        b1.s[4]=f2bf(g1.x); b1.s[5]=f2bf(g1.y); b1.s[6]=f2bf(g1.z); b1.s[7]=f2bf(g1.w);
        #pragma unroll
        for (int mt = 0; mt < 8; ++mt) {
            const bf16x8 a = *(const bf16x8*)&w1s[(mt * 16 + l16) * 132 + ks * 32 + quad * 8];
            acc[mt][0] = __builtin_amdgcn_mfma_f32_16x16x32_bf16(a, b0.v, acc[mt][0], 0, 0, 0);
            acc[mt][1] = __builtin_amdgcn_mfma_f32_16x16x32_bf16(a, b1.v, acc[mt][1], 0, 0, 0);
        }
    }

    #pragma unroll
    for (int nt = 0; nt < 2; ++nt) {
        const int rn = n0 + nt * 16 + l16;
        if (rn < M) {
            u8* rowp = T + (size_t)rn * 128 + quad * 4;
            #pragma unroll
            for (int mt = 0; mt < 8; ++mt) {
                const f32x4 a = acc[mt][nt];
                int p = __builtin_amdgcn_cvt_pk_fp8_f32(a[0] * FP8_SCALE, a[1] * FP8_SCALE, 0, 0);
                p = __builtin_amdgcn_cvt_pk_fp8_f32(a[2] * FP8_SCALE, a[3] * FP8_SCALE, p, 1);
                *(u32*)(rowp + mt * 16) = (u32)p;
            }
        }
    }
}

// ---------------------------------------------------------------------------
// Gather+sum from fp8 tables -> rep (cur|prev, rescale + b1 folded).
// Block = 4 batch rows; thread = 8 B (8 fp8 cols) x 32 rows, ping-pong
// 8-deep load batches. Decode via v_cvt_pk_f32_fp8, fp32 accumulate.
// ---------------------------------------------------------------------------
__global__ __launch_bounds__(256) void gather_rep(
    const int* __restrict__ diag, const int* __restrict__ proc,
    const int* __restrict__ pdiag, const int* __restrict__ pproc,
    const u8* __restrict__ Td, const u8* __restrict__ Tp,
    const float* __restrict__ b1, u16* __restrict__ rep)
{
    __shared__ int   sidx[528];
    __shared__ float sred[128][8];
    const int t = threadIdx.x;

    for (int i = t; i < 512; i += 256) {
        const int s = i >> 7, bg = (i >> 5) & 3, l = i & 31;
        const int* cp = (bg == 0) ? diag : (bg == 1) ? proc : (bg == 2) ? pdiag : pproc;
        sidx[s * 132 + bg * 33 + l] = cp[(blockIdx.x * 4 + s) * 32 + l];
    }
    __syncthreads();

    const int sub = t >> 6, bag = (t >> 4) & 3, lc = t & 15;
    const u8* tbl = (bag & 1) ? Tp : Td;
    const int* myidx = &sidx[sub * 132 + bag * 33];

    f32x2 s0 = {0.f,0.f}, s1 = {0.f,0.f}, s2 = {0.f,0.f}, s3 = {0.f,0.f};
    uint2 va[8], vb[8];
    #pragma unroll
    for (int j = 0; j < 8; ++j)
        va[j] = *(const uint2*)(tbl + (size_t)myidx[j] * 128 + lc * 8);
    #pragma unroll
    for (int j = 0; j < 8; ++j)
        vb[j] = *(const uint2*)(tbl + (size_t)myidx[8 + j] * 128 + lc * 8);

#define CONSUME(V) do { \
    _Pragma("unroll") \
    for (int j = 0; j < 8; ++j) { \
        s0 += __builtin_amdgcn_cvt_pk_f32_fp8((int)V[j].x, 0); \
        s1 += __builtin_amdgcn_cvt_pk_f32_fp8((int)V[j].x, 1); \
        s2 += __builtin_amdgcn_cvt_pk_f32_fp8((int)V[j].y, 0); \
        s3 += __builtin_amdgcn_cvt_pk_f32_fp8((int)V[j].y, 1); \
    } } while (0)

    {
        uint2 tmp[8];
        #pragma unroll
        for (int j = 0; j < 8; ++j)
            tmp[j] = *(const uint2*)(tbl + (size_t)myidx[16 + j] * 128 + lc * 8);
        CONSUME(va);
        #pragma unroll
        for (int j = 0; j < 8; ++j) va[j] = tmp[j];
    }
    {
        uint2 tmp[8];
        #pragma unroll
        for (int j = 0; j < 8; ++j)
            tmp[j] = *(const uint2*)(tbl + (size_t)myidx[24 + j] * 128 + lc * 8);
        CONSUME(vb);
        #pragma unroll
        for (int j = 0; j < 8; ++j) vb[j] = tmp[j];
    }
    CONSUME(va);
    CONSUME(vb);
#undef CONSUME

    const int oid = sub * 32 + (bag >> 1) * 16 + lc;
    if (bag & 1) {
        *(float4*)&sred[oid][0] = make_float4(s0.x, s0.y, s1.x, s1.y);
        *(float4*)&sred[oid][4] = make_float4(s2.x, s2.y, s3.x, s3.y);
    }
    __syncthreads();
    if (!(bag & 1)) {
        const float4 p0 = *(const float4*)&sred[oid][0];
        const float4 p1 = *(const float4*)&sred[oid][4];
        const float4 c0 = *(const float4*)(b1 + lc * 8);
        const float4 c1 = *(const float4*)(b1 + lc * 8 + 4);
        const float t0 = (s0.x + p0.x) * FP8_INV + c0.x;
        const float t1 = (s0.y + p0.y) * FP8_INV + c0.y;
        const float t2 = (s1.x + p0.z) * FP8_INV + c0.z;
        const float t3 = (s1.y + p0.w) * FP8_INV + c0.w;
        const float t4 = (s2.x + p1.x) * FP8_INV + c1.x;
        const float t5 = (s2.y + p1.y) * FP8_INV + c1.y;
        const float t6 = (s3.x + p1.z) * FP8_INV + c1.z;
        const float t7 = (s3.y + p1.w) * FP8_INV + c1.w;
        uint4 o;
        o.x = (u32)f2bf(t0) | ((u32)f2bf(t1) << 16);
        o.y = (u32)f2bf(t2) | ((u32)f2bf(t3) << 16);
        o.z = (u32)f2bf(t4) | ((u32)f2bf(t5) << 16);
        o.w = (u32)f2bf(t6) | ((u32)f2bf(t7) << 16);
        const int b = blockIdx.x * 4 + sub;
        *(uint4*)(rep + (size_t)b * 256 + (bag >> 1) * 128 + lc * 8) = o;
    }
}

// ---------------------------------------------------------------------------
// Fused GEMM2+GEMM3 (unchanged from R3). Block = 32-row M-tile, grid 512.
// ---------------------------------------------------------------------------
__global__ __launch_bounds__(256) void gemm23(
    const u16* __restrict__ rep, const u16* __restrict__ W2b,
    const float* __restrict__ b2, const u16* __restrict__ W3b,
    const float* __restrict__ b3, float* __restrict__ out)
{
    __shared__ u16 hs[32][264];
    const int wave = threadIdx.x >> 6, lane = threadIdx.x & 63;
    const int quad = lane >> 4, l16 = lane & 15;
    const int mBase = blockIdx.x * 32;

    // ---- phase 1: h = relu(rep @ W2^T + b2) -> LDS ----
    {
        const int mrow = mBase + (wave & 1) * 16 + l16;
        const int ncol0 = (wave >> 1) * 128;
        const u16* aP = rep + (size_t)mrow * 256 + quad * 8;
        bf16x8 a[8];
        #pragma unroll
        for (int ks = 0; ks < 8; ++ks) a[ks] = *(const bf16x8*)(aP + ks * 32);

        #pragma unroll
        for (int nt = 0; nt < 8; ++nt) {
            const int col = ncol0 + nt * 16 + l16;
            const u16* wP = W2b + (size_t)col * 256 + quad * 8;
            f32x4 acc = {0.f, 0.f, 0.f, 0.f};
            #pragma unroll
            for (int ks = 0; ks < 8; ++ks) {
                const bf16x8 b = *(const bf16x8*)(wP + ks * 32);
                acc = __builtin_amdgcn_mfma_f32_16x16x32_bf16(a[ks], b, acc, 0, 0, 0);
            }
            const float bv = b2[col];
            #pragma unroll
            for (int r = 0; r < 4; ++r) {
                float v = acc[r] + bv;
                v = v > 0.f ? v : 0.f;
                hs[(wave & 1) * 16 + quad * 4 + r][col] = f2bf(v);
            }
        }
    }
    __syncthreads();

    // ---- phase 2: out = sigmoid(h @ W3^T + b3) ----
    const int colW = wave * 256;
    #pragma unroll
    for (int nc = 0; nc < 4; ++nc) {
        f32x4 acc[2][4];
        #pragma unroll
        for (int mt = 0; mt < 2; ++mt)
            #pragma unroll
            for (int nti = 0; nti < 4; ++nti) acc[mt][nti] = (f32x4){0.f,0.f,0.f,0.f};

        #pragma unroll
        for (int ks = 0; ks < 8; ++ks) {
            bf16x8 af[2];
            #pragma unroll
            for (int mt = 0; mt < 2; ++mt)
                af[mt] = *(const bf16x8*)&hs[mt * 16 + l16][quad * 8 + ks * 32];
            #pragma unroll
            for (int nti = 0; nti < 4; ++nti) {
                const int wrow = colW + nc * 64 + nti * 16 + l16;
                const bf16x8 b = *(const bf16x8*)(W3b + (size_t)wrow * 256 + quad * 8 + ks * 32);
                acc[0][nti] = __builtin_amdgcn_mfma_f32_16x16x32_bf16(af[0], b, acc[0][nti], 0, 0, 0);
                acc[1][nti] = __builtin_amdgcn_mfma_f32_16x16x32_bf16(af[1], b, acc[1][nti], 0, 0, 0);
            }
        }
        #pragma unroll
        for (int nti = 0; nti < 4; ++nti) {
            const int col = colW + nc * 64 + nti * 16 + l16;
            if (col < MED) {
                const float bv = b3[col];
                #pragma unroll
                for (int mt = 0; mt < 2; ++mt) {
                    #pragma unroll
                    for (int r = 0; r < 4; ++r) {
                        const float v = acc[mt][nti][r] + bv;
                        out[(size_t)(mBase + mt * 16 + quad * 4 + r) * MED + col] =
                            1.0f / (1.0f + __expf(-v));
                    }
                }
            }
        }
    }
}

// ---------------------------------------------------------------------------
extern "C" void kernel_launch(void* const* d_in, const int* in_sizes, int n_in,
                              void* d_out, int out_size, void* d_ws, size_t ws_size,
                              hipStream_t stream)
{
    const int*   diag  = (const int*)d_in[0];
    const int*   proc  = (const int*)d_in[1];
    const int*   pdiag = (const int*)d_in[2];
    const int*   pproc = (const int*)d_in[3];
    const float* demb  = (const float*)d_in[4];
    const float* pemb  = (const float*)d_in[5];
    const float* W1    = (const float*)d_in[6];
    const float* b1    = (const float*)d_in[7];
    const float* W2    = (const float*)d_in[8];
    const float* b2    = (const float*)d_in[9];
    const float* W3    = (const float*)d_in[10];
    const float* b3    = (const float*)d_in[11];

    char* ws = (char*)d_ws;
    // ws layout (bytes), total ~28.2 MB:
    //   Td  [100000,128] fp8  : 0          .. 12,800,000
    //   Tp  [ 50000,128] fp8  : 12,800,000 .. 19,200,000
    //   rep [16384,256]  bf16 : 19,200,000 .. 27,588,608
    //   W2b [256,256]    bf16 : 27,588,608 .. 27,719,680
    //   W3b [1024,256]   bf16 : 27,719,680 .. 28,243,968
    u8*  Td  = (u8*)ws;
    u8*  Tp  = (u8*)(ws + 12800000);
    u16* rep = (u16*)(ws + 19200000);
    u16* W2b = (u16*)(ws + 27588608);
    u16* W3b = (u16*)(ws + 27719680);

    prep_kernel<<<NTR + NCV, 256, 0, stream>>>(demb, pemb, W1, W2, W3, Td, Tp, W2b, W3b);
    gather_rep<<<NB / 4, 256, 0, stream>>>(diag, proc, pdiag, pproc, Td, Tp, b1, rep);
    gemm23<<<512, 256, 0, stream>>>(rep, W2b, b2, W3b, b3, (float*)d_out);
}